// Round 1
// baseline (382.621 us; speedup 1.0000x reference)
//
#include <hip/hip_runtime.h>
#include <hip/hip_bf16.h>
#include <stdint.h>

// RelationalMSG: out = x + relu([x;agg]@W2+b2), agg = segsum(relu([x_s;x_d]@W1+b1), dst)
// N=50000, D=128, E=600000. bf16 MFMA (16x16x32) for both MLPs; fp32 atomics for scatter.

typedef __attribute__((ext_vector_type(8))) short short8;   // 8 bf16 = 4 VGPRs (MFMA A/B frag)
typedef __attribute__((ext_vector_type(4))) float floatx4;  // MFMA C/D frag

#define D 128
#define K2 256          // concat dim
#define TM 64           // edge/node rows per block tile
#define PAD_K 264       // 256 + 8 bf16 pad -> 528B row stride, 16B aligned, 2-way max bank conflict

static __device__ __forceinline__ unsigned short f2bf(float f) {
    union { float f; unsigned int u; } v; v.f = f;
    unsigned int r = (v.u + 0x7fffu + ((v.u >> 16) & 1u)) >> 16; // RNE
    return (unsigned short)r;
}

__global__ void k_convert_x(const float* __restrict__ x, unsigned short* __restrict__ xb, int n4) {
    int i = blockIdx.x * blockDim.x + threadIdx.x;
    if (i < n4) {
        float4 v = ((const float4*)x)[i];
        ushort4 o;
        o.x = f2bf(v.x); o.y = f2bf(v.y); o.z = f2bf(v.z); o.w = f2bf(v.w);
        ((ushort4*)xb)[i] = o;
    }
}

// W [K2][D] fp32 -> bf16 in B-fragment order: frag[(kk*8+n)*64+lane][j] = W[kk*32+(lane>>4)*8+j][n*16+(lane&15)]
__global__ void k_convert_w(const float* __restrict__ W, unsigned short* __restrict__ wf) {
    int tid = blockIdx.x * blockDim.x + threadIdx.x; // 32768 threads
    int j = tid & 7;
    int lane = (tid >> 3) & 63;
    int n = (tid >> 9) & 7;
    int kk = tid >> 12;
    int k = kk * 32 + (lane >> 4) * 8 + j;
    int c = n * 16 + (lane & 15);
    wf[tid] = f2bf(W[k * D + c]);
}

// Edge message kernel: persistent blocks, 64-edge tiles.
// Block = 4 waves; wave w owns column tiles {2w, 2w+1} (W1 frags register-resident),
// computes all 64 rows (4 M-tiles), scatters relu(msg) via fp32 atomics (skip zeros).
__global__ __launch_bounds__(256) void k_edge(
    const unsigned short* __restrict__ xb,
    const int* __restrict__ src,
    const int* __restrict__ dst,
    const unsigned short* __restrict__ w1f,
    const float* __restrict__ b1,
    float* __restrict__ agg,
    int E)
{
    __shared__ unsigned short pair[TM][PAD_K];
    __shared__ int sdst[TM];
    const int tid = threadIdx.x;
    const int lane = tid & 63, wave = tid >> 6;
    const int quad = lane >> 4, col = lane & 15;

    // register-resident B fragments for this wave's 2 column tiles
    short8 bfr[2][8];
#pragma unroll
    for (int kk = 0; kk < 8; kk++)
#pragma unroll
        for (int c = 0; c < 2; c++) {
            int ct = wave * 2 + c;
            bfr[c][kk] = ((const short8*)w1f)[(kk * 8 + ct) * 64 + lane];
        }
    float bias[2];
    bias[0] = b1[(wave * 2) * 16 + col];
    bias[1] = b1[(wave * 2 + 1) * 16 + col];

    const int numTiles = (E + TM - 1) / TM;
    for (int tile = blockIdx.x; tile < numTiles; tile += gridDim.x) {
        const int e0 = tile * TM;
        if (tid < TM) {
            int ee = e0 + tid; if (ee >= E) ee = E - 1;
            sdst[tid] = dst[ee];
        }
        // gather: 64 edges x 2 rows x 16 chunks of 16B (bf16) = 2048 chunks
#pragma unroll
        for (int it = 0; it < 8; it++) {
            int i = it * 256 + tid;
            int r = i >> 5, h = (i >> 4) & 1, c = i & 15;
            int ee = e0 + r; if (ee >= E) ee = E - 1;
            int node = h ? dst[ee] : src[ee];
            short8 v = ((const short8*)xb)[node * 16 + c];
            *(short8*)&pair[r][h * 128 + c * 8] = v;
        }
        __syncthreads();

        floatx4 acc[4][2];
#pragma unroll
        for (int mt = 0; mt < 4; mt++)
#pragma unroll
            for (int c = 0; c < 2; c++)
#pragma unroll
                for (int q = 0; q < 4; q++) acc[mt][c][q] = 0.f;

#pragma unroll
        for (int kk = 0; kk < 8; kk++) {
            short8 af[4];
#pragma unroll
            for (int mt = 0; mt < 4; mt++)
                af[mt] = *(const short8*)&pair[mt * 16 + col][kk * 32 + quad * 8];
#pragma unroll
            for (int mt = 0; mt < 4; mt++) {
                acc[mt][0] = __builtin_amdgcn_mfma_f32_16x16x32_bf16(af[mt], bfr[0][kk], acc[mt][0], 0, 0, 0);
                acc[mt][1] = __builtin_amdgcn_mfma_f32_16x16x32_bf16(af[mt], bfr[1][kk], acc[mt][1], 0, 0, 0);
            }
        }
        // scatter: C/D layout col=lane&15, row=quad*4+reg
#pragma unroll
        for (int mt = 0; mt < 4; mt++)
#pragma unroll
            for (int c = 0; c < 2; c++) {
                int colg = (wave * 2 + c) * 16 + col;
#pragma unroll
                for (int r4 = 0; r4 < 4; r4++) {
                    int row = mt * 16 + quad * 4 + r4;
                    float v = acc[mt][c][r4] + bias[c];
                    if (e0 + row < E && v > 0.f)
                        atomicAdd(&agg[(long)sdst[row] * D + colg], v);
                }
            }
        __syncthreads();
    }
}

// Node update: rows = [xb[node] ; bf16(agg[node])], out = x + relu(row @ W2 + b2)
__global__ __launch_bounds__(256) void k_node(
    const unsigned short* __restrict__ xb,
    const float* __restrict__ x,
    const float* __restrict__ agg,
    const unsigned short* __restrict__ w2f,
    const float* __restrict__ b2,
    float* __restrict__ out,
    int N)
{
    __shared__ unsigned short pair[TM][PAD_K];
    const int tid = threadIdx.x;
    const int lane = tid & 63, wave = tid >> 6;
    const int quad = lane >> 4, col = lane & 15;

    short8 bfr[2][8];
#pragma unroll
    for (int kk = 0; kk < 8; kk++)
#pragma unroll
        for (int c = 0; c < 2; c++) {
            int ct = wave * 2 + c;
            bfr[c][kk] = ((const short8*)w2f)[(kk * 8 + ct) * 64 + lane];
        }
    float bias[2];
    bias[0] = b2[(wave * 2) * 16 + col];
    bias[1] = b2[(wave * 2 + 1) * 16 + col];

    const int numTiles = (N + TM - 1) / TM;
    for (int tile = blockIdx.x; tile < numTiles; tile += gridDim.x) {
        const int n0 = tile * TM;
        // x half: 64 rows x 16 chunks of 16B
#pragma unroll
        for (int it = 0; it < 4; it++) {
            int i = it * 256 + tid;
            int r = i >> 4, c = i & 15;
            int node = n0 + r;
            short8 v;
            if (node < N) v = ((const short8*)xb)[node * 16 + c];
            else { for (int q = 0; q < 8; q++) v[q] = 0; }
            *(short8*)&pair[r][c * 8] = v;
        }
        // agg half: 64 rows x 32 chunks (float4 -> 4 bf16)
#pragma unroll
        for (int it = 0; it < 8; it++) {
            int i = it * 256 + tid;
            int r = i >> 5, c = i & 31;
            int node = n0 + r;
            ushort4 o = {0, 0, 0, 0};
            if (node < N) {
                float4 v = ((const float4*)agg)[node * 32 + c];
                o.x = f2bf(v.x); o.y = f2bf(v.y); o.z = f2bf(v.z); o.w = f2bf(v.w);
            }
            *(ushort4*)&pair[r][128 + c * 4] = o;
        }
        __syncthreads();

        floatx4 acc[4][2];
#pragma unroll
        for (int mt = 0; mt < 4; mt++)
#pragma unroll
            for (int c = 0; c < 2; c++)
#pragma unroll
                for (int q = 0; q < 4; q++) acc[mt][c][q] = 0.f;

#pragma unroll
        for (int kk = 0; kk < 8; kk++) {
            short8 af[4];
#pragma unroll
            for (int mt = 0; mt < 4; mt++)
                af[mt] = *(const short8*)&pair[mt * 16 + col][kk * 32 + quad * 8];
#pragma unroll
            for (int mt = 0; mt < 4; mt++) {
                acc[mt][0] = __builtin_amdgcn_mfma_f32_16x16x32_bf16(af[mt], bfr[0][kk], acc[mt][0], 0, 0, 0);
                acc[mt][1] = __builtin_amdgcn_mfma_f32_16x16x32_bf16(af[mt], bfr[1][kk], acc[mt][1], 0, 0, 0);
            }
        }
#pragma unroll
        for (int mt = 0; mt < 4; mt++)
#pragma unroll
            for (int c = 0; c < 2; c++) {
                int colg = (wave * 2 + c) * 16 + col;
#pragma unroll
                for (int r4 = 0; r4 < 4; r4++) {
                    int row = mt * 16 + quad * 4 + r4;
                    int node = n0 + row;
                    if (node < N) {
                        float v = acc[mt][c][r4] + bias[c];
                        v = v > 0.f ? v : 0.f;
                        out[(long)node * D + colg] = x[(long)node * D + colg] + v;
                    }
                }
            }
        __syncthreads();
    }
}

extern "C" void kernel_launch(void* const* d_in, const int* in_sizes, int n_in,
                              void* d_out, int out_size, void* d_ws, size_t ws_size,
                              hipStream_t stream)
{
    const float* x   = (const float*)d_in[0];
    const int* esrc  = (const int*)d_in[1];
    const int* edst  = (const int*)d_in[2];
    const float* W1  = (const float*)d_in[3];
    const float* b1  = (const float*)d_in[4];
    const float* W2  = (const float*)d_in[5];
    const float* b2  = (const float*)d_in[6];
    float* out = (float*)d_out;

    const int ND = in_sizes[0];   // N*D
    const int N  = ND / D;        // 50000
    const int E  = in_sizes[1];   // 600000

    // workspace layout (all 256B-aligned): agg fp32 | xb bf16 | w1f | w2f
    char* ws = (char*)d_ws;
    float* agg = (float*)ws;
    size_t aggB = (size_t)ND * sizeof(float);
    unsigned short* xb = (unsigned short*)(ws + aggB);
    size_t xbB = (size_t)ND * sizeof(unsigned short);
    unsigned short* w1f = (unsigned short*)(ws + aggB + xbB);
    unsigned short* w2f = w1f + K2 * D;

    hipMemsetAsync(agg, 0, aggB, stream);
    int n4 = ND / 4;
    k_convert_x<<<(n4 + 255) / 256, 256, 0, stream>>>(x, xb, n4);
    k_convert_w<<<128, 256, 0, stream>>>(W1, w1f);
    k_convert_w<<<128, 256, 0, stream>>>(W2, w2f);

    k_edge<<<768, 256, 0, stream>>>(xb, esrc, edst, w1f, b1, agg, E);

    int nTiles = (N + TM - 1) / TM;
    k_node<<<nTiles, 256, 0, stream>>>(xb, x, agg, w2f, b2, out, N);
}